// Round 11
// baseline (213.285 us; speedup 1.0000x reference)
//
#include <hip/hip_runtime.h>
#include <hip/hip_fp16.h>

#define N_USERS 50000
#define N_ITEMS 100000
#define N_NODES (N_USERS + N_ITEMS)      // 150000
#define DIM 64
#define NCB 256                          // coarse buckets
#define CROWS ((N_NODES + NCB - 1) / NCB)    // 586 rows per bucket (last: 570)
#define CAP 6144                         // temp capacity per bucket (avg 4688)
#define CHUNK 4096                       // edges per binA block

// ---------------------------------------------------------------------------
// init: buf0 = fp16(concat(user, item)); gcur[b] = b*CAP
// ---------------------------------------------------------------------------
__global__ void init_kernel(const float4* __restrict__ user,
                            const float4* __restrict__ item,
                            uint2* __restrict__ buf0,
                            int* __restrict__ gcur,
                            int nUser4, int nTotal4) {
    int stride = gridDim.x * blockDim.x;
    int t0 = blockIdx.x * blockDim.x + threadIdx.x;
    for (int i = t0; i < nTotal4; i += stride) {
        float4 v = (i < nUser4) ? user[i] : item[i - nUser4];
        __half2 h0 = __floats2half2_rn(v.x, v.y);
        __half2 h1 = __floats2half2_rn(v.z, v.w);
        uint2 o;
        o.x = *(const unsigned int*)&h0;
        o.y = *(const unsigned int*)&h1;
        buf0[i] = o;
    }
    for (int i = t0; i < NCB; i += stride) gcur[i] = i * CAP;
}

// ---------------------------------------------------------------------------
// binA: per-4096-edge chunk LDS counting sort by coarse bucket (r/CROWS),
// then append each bucket's run (~16 edges) to its private temp region with
// ONE cursor bump + coalesced writes. Payload: x = col | rlocal<<18,
// y = val bits (col < 2^18, rlocal < 586 < 2^10).
// ---------------------------------------------------------------------------
__global__ __launch_bounds__(256) void binA_kernel(const int* __restrict__ rows,
                                                   const int* __restrict__ cols,
                                                   const float* __restrict__ vals,
                                                   int* __restrict__ gcur,
                                                   uint2* __restrict__ temp, int nE) {
    __shared__ uint2 stage[CHUNK];                  // 32KB
    __shared__ int hist[NCB], off0[NCB], cur[NCB], gbase[NCB];
    __shared__ int s0[NCB], s1[NCB];
    int t = threadIdx.x;
    int beg = blockIdx.x * CHUNK;
    int end = beg + CHUNK; if (end > nE) end = nE;
    hist[t] = 0;                                    // NCB == blockDim == 256
    __syncthreads();
    // pass 1: count coarse buckets
    for (int i = beg + t; i < end; i += 256) {
        int r = __builtin_nontemporal_load(rows + i);
        atomicAdd(&hist[r / CROWS], 1);
    }
    __syncthreads();
    // parallel exclusive scan of hist (Hillis-Steele, double buffer)
    s0[t] = hist[t];
    __syncthreads();
    int* sA = s0; int* sB = s1;
    for (int off = 1; off < NCB; off <<= 1) {
        int v = sA[t] + (t >= off ? sA[t - off] : 0);
        sB[t] = v;
        __syncthreads();
        int* tmp = sA; sA = sB; sB = tmp;
    }
    off0[t] = sA[t] - hist[t];
    cur[t]  = off0[t];
    __syncthreads();
    // pass 2: place into stage, sorted by bucket (rows re-read: L2-hot)
    for (int i = beg + t; i < end; i += 256) {
        int   r = rows[i];
        int   c = __builtin_nontemporal_load(cols + i);
        float v = __builtin_nontemporal_load(vals + i);
        int  cb = r / CROWS;
        int pos = atomicAdd(&cur[cb], 1);
        uint2 p;
        p.x = (unsigned)c | ((unsigned)(r - cb * CROWS) << 18);
        p.y = __float_as_uint(v);
        stage[pos] = p;
    }
    __syncthreads();
    gbase[t] = hist[t] ? atomicAdd(&gcur[t], hist[t]) : 0;
    __syncthreads();
    // flush: 16-lane-group coalesced run copies (runs avg ~16 edges)
    int hg = t >> 4, ln = t & 15;
    for (int b = hg; b < NCB; b += 16) {
        int len = hist[b], o0 = off0[b], gb = gbase[b];
        for (int j = ln; j < len; j += 16) temp[gb + j] = stage[o0 + j];
    }
}

// ---------------------------------------------------------------------------
// binB: one 512-thread block per coarse bucket. Count local rows in LDS,
// parallel exclusive scan, emit row_start, place edges at exact CSR
// positions (write window ~37KB -> full L2 line merging).
// Output edge format: float2{col_as_int_bits, val}.
// ---------------------------------------------------------------------------
__global__ __launch_bounds__(512) void binB_kernel(const int* __restrict__ gcur,
                                                   const uint2* __restrict__ temp,
                                                   float2* __restrict__ ebuf,
                                                   int* __restrict__ row_start) {
    __shared__ int rcnt[CROWS];
    __shared__ int rcur[CROWS];
    __shared__ int p0[512], p1[512];
    __shared__ int cs0[NCB], cs1[NCB];
    int b = blockIdx.x;
    int t = threadIdx.x;
    // bucket counts -> inclusive scan (for cstart / cnt_b)
    if (t < NCB) cs0[t] = gcur[t] - t * CAP;
    __syncthreads();
    int* cA = cs0; int* cB = cs1;
    for (int off = 1; off < NCB; off <<= 1) {
        int v = 0;
        if (t < NCB) v = cA[t] + (t >= off ? cA[t - off] : 0);
        if (t < NCB) cB[t] = v;
        __syncthreads();
        int* tmp = cA; cA = cB; cB = tmp;
    }
    int cstart = (b == 0) ? 0 : cA[b - 1];
    int cnt_b  = cA[b] - cstart;
    for (int i = t; i < CROWS; i += 512) rcnt[i] = 0;
    __syncthreads();
    int base = b * CAP;
    // count local rows
    for (int i = t; i < cnt_b; i += 512)
        atomicAdd(&rcnt[temp[base + i].x >> 18], 1);
    __syncthreads();
    // exclusive scan of rcnt: 2 items/thread serial + parallel scan of partials
    int s = 0;
    #pragma unroll
    for (int k = 0; k < 2; ++k) {
        int idx = t * 2 + k;
        if (idx < CROWS) { int v = rcnt[idx]; rcnt[idx] = s; s += v; }
    }
    p0[t] = s;
    __syncthreads();
    int* pA = p0; int* pB = p1;
    for (int off = 1; off < 512; off <<= 1) {
        int v = pA[t] + (t >= off ? pA[t - off] : 0);
        pB[t] = v;
        __syncthreads();
        int* tmp = pA; pA = pB; pB = tmp;
    }
    int add = (t == 0) ? 0 : pA[t - 1];
    #pragma unroll
    for (int k = 0; k < 2; ++k) {
        int idx = t * 2 + k;
        if (idx < CROWS) rcnt[idx] += add;
    }
    __syncthreads();
    // emit row_start + init cursors (last bucket has 570 rows)
    for (int i = t; i < CROWS; i += 512) {
        int gr = b * CROWS + i;
        if (gr < N_NODES) row_start[gr] = cstart + rcnt[i];
        rcur[i] = rcnt[i];
    }
    if (b == NCB - 1 && t == 0) row_start[N_NODES] = cstart + cnt_b;
    __syncthreads();
    // place at exact CSR positions (L2-merged ~37KB window)
    for (int i = t; i < cnt_b; i += 512) {
        uint2 p  = temp[base + i];
        int   rl = p.x >> 18;
        int  pos = cstart + atomicAdd(&rcur[rl], 1);
        ebuf[pos] = make_float2(__int_as_float((int)(p.x & 0x3FFFF)),
                                __uint_as_float(p.y));
    }
}

// ---------------------------------------------------------------------------
// CSR SpMM, gather form, 8 rows per wave: 8 lanes per row, each lane holds
// 8 halfs (uint4, 16B). Per gather instruction the wave moves 1KB (8 rows);
// 2x the in-flight bytes of the 4-row/uint2 variant at the same per-lane
// ILP (= row degree). N_NODES % 8 == 0 -> no partial waves.
// MODE 0: dst8[r] = fp16(sum)
// MODE 1: out[r] = (emb_fp32[r] + prev[r] + sum) / 3
// ---------------------------------------------------------------------------
#define GBLOCK8(U)                                                             \
    {                                                                          \
        float2 ev[U];                                                          \
        _Pragma("unroll") for (int j = 0; j < U; ++j) ev[j] = edges[i + j];    \
        uint4 sv[U];                                                           \
        _Pragma("unroll") for (int j = 0; j < U; ++j)                          \
            sv[j] = src8[(size_t)__float_as_int(ev[j].x) * 8 + l8];            \
        _Pragma("unroll") for (int j = 0; j < U; ++j) {                        \
            float v = ev[j].y;                                                 \
            float2 a0 = __half22float2(*(__half2*)&sv[j].x);                   \
            float2 a1 = __half22float2(*(__half2*)&sv[j].y);                   \
            float2 a2 = __half22float2(*(__half2*)&sv[j].z);                   \
            float2 a3 = __half22float2(*(__half2*)&sv[j].w);                   \
            acc0.x = fmaf(v, a0.x, acc0.x);                                    \
            acc0.y = fmaf(v, a0.y, acc0.y);                                    \
            acc0.z = fmaf(v, a1.x, acc0.z);                                    \
            acc0.w = fmaf(v, a1.y, acc0.w);                                    \
            acc1.x = fmaf(v, a2.x, acc1.x);                                    \
            acc1.y = fmaf(v, a2.y, acc1.y);                                    \
            acc1.z = fmaf(v, a3.x, acc1.z);                                    \
            acc1.w = fmaf(v, a3.y, acc1.w);                                    \
        }                                                                      \
        i += U;                                                                \
    }

template <int MODE>
__global__ void spmm_csr8_kernel(const int* __restrict__ row_start,
                                 const float2* __restrict__ edges,
                                 const uint4* __restrict__ src8,
                                 uint4* __restrict__ dst8,
                                 const float4* __restrict__ user4,
                                 const float4* __restrict__ item4,
                                 const uint4* __restrict__ prev8,
                                 float4* __restrict__ out4) {
    int wave = (blockIdx.x * blockDim.x + threadIdx.x) >> 6;
    int lane = threadIdx.x & 63;
    int sub  = lane >> 3;                 // 0..7: row within wave
    int l8   = lane & 7;                  // uint4 index within row
    int row  = wave * 8 + sub;
    if (row >= N_NODES) return;
    int i   = row_start[row];
    int end = row_start[row + 1];
    float4 acc0 = make_float4(0.f, 0.f, 0.f, 0.f);
    float4 acc1 = make_float4(0.f, 0.f, 0.f, 0.f);

    while (end - i >= 8) GBLOCK8(8)
    if (end - i >= 4)    GBLOCK8(4)
    if (end - i >= 2)    GBLOCK8(2)
    if (end - i >= 1)    GBLOCK8(1)

    size_t o = (size_t)row * 8 + l8;      // uint4 units
    if (MODE == 0) {
        __half2 h0 = __floats2half2_rn(acc0.x, acc0.y);
        __half2 h1 = __floats2half2_rn(acc0.z, acc0.w);
        __half2 h2 = __floats2half2_rn(acc1.x, acc1.y);
        __half2 h3 = __floats2half2_rn(acc1.z, acc1.w);
        uint4 p;
        p.x = *(unsigned*)&h0;
        p.y = *(unsigned*)&h1;
        p.z = *(unsigned*)&h2;
        p.w = *(unsigned*)&h3;
        dst8[o] = p;
    } else {
        size_t of4 = (size_t)row * 16 + (size_t)l8 * 2;   // float4 units
        float4 e0, e1;
        if (row < N_USERS) {
            e0 = user4[of4];
            e1 = user4[of4 + 1];
        } else {
            size_t oi = of4 - (size_t)N_USERS * 16;
            e0 = item4[oi];
            e1 = item4[oi + 1];
        }
        uint4 pv = prev8[o];
        float2 q0 = __half22float2(*(__half2*)&pv.x);
        float2 q1 = __half22float2(*(__half2*)&pv.y);
        float2 q2 = __half22float2(*(__half2*)&pv.z);
        float2 q3 = __half22float2(*(__half2*)&pv.w);
        const float s = 1.0f / 3.0f;
        out4[of4]     = make_float4((e0.x + q0.x + acc0.x) * s,
                                    (e0.y + q0.y + acc0.y) * s,
                                    (e0.z + q1.x + acc0.z) * s,
                                    (e0.w + q1.y + acc0.w) * s);
        out4[of4 + 1] = make_float4((e1.x + q2.x + acc1.x) * s,
                                    (e1.y + q2.y + acc1.y) * s,
                                    (e1.z + q3.x + acc1.z) * s,
                                    (e1.w + q3.y + acc1.w) * s);
    }
}

extern "C" void kernel_launch(void* const* d_in, const int* in_sizes, int n_in,
                              void* d_out, int out_size, void* d_ws, size_t ws_size,
                              hipStream_t stream) {
    const float* user = (const float*)d_in[0];
    const float* item = (const float*)d_in[1];
    const int*   rows = (const int*)d_in[2];
    const int*   cols = (const int*)d_in[3];
    const float* vals = (const float*)d_in[4];
    float* out = (float*)d_out;

    const int    nEdges = in_sizes[2];
    const size_t nNodeF = (size_t)N_NODES * DIM;      // 9.6M elements

    // workspace: buf0(half) | buf1(half) | ebuf(float2 E) | temp(uint2 NCB*CAP)
    //            | gcur(NCB) | row_start(N+1)
    __half* buf0      = (__half*)d_ws;
    __half* buf1      = buf0 + nNodeF;
    float2* ebuf      = (float2*)(buf1 + nNodeF);
    uint2*  temp      = (uint2*)(ebuf + nEdges);
    int*    gcur      = (int*)(temp + (size_t)NCB * CAP);
    int*    row_start = gcur + NCB;

    const int n4      = (int)(nNodeF / 4);
    const int nUser4  = N_USERS * DIM / 4;
    const int aBlocks = (nEdges + CHUNK - 1) / CHUNK; // 293
    const int nWaves  = N_NODES / 8;                  // 18750, exact
    const int spmmBlocks = (nWaves + 3) / 4;          // 4 waves/block

    // 1. buf0 = fp16(emb); gcur[b] = b*CAP
    init_kernel<<<512, 256, 0, stream>>>((const float4*)user, (const float4*)item,
                                         (uint2*)buf0, gcur, nUser4, n4);
    // 2. coarse counting-sort (coalesced appends)
    binA_kernel<<<aBlocks, 256, 0, stream>>>(rows, cols, vals, gcur, temp, nEdges);
    // 3. exact CSR within each coarse bucket (L2-merged window) + row_start
    binB_kernel<<<NCB, 512, 0, stream>>>(gcur, temp, ebuf, row_start);
    // 4. e1 = A @ emb -> buf1 (fp16)
    spmm_csr8_kernel<0><<<spmmBlocks, 256, 0, stream>>>(row_start, ebuf,
                                                        (const uint4*)buf0,
                                                        (uint4*)buf1,
                                                        nullptr, nullptr, nullptr,
                                                        nullptr);
    // 5. out = (emb_fp32 + e1 + A @ e1) / 3
    spmm_csr8_kernel<1><<<spmmBlocks, 256, 0, stream>>>(row_start, ebuf,
                                                        (const uint4*)buf1,
                                                        nullptr,
                                                        (const float4*)user,
                                                        (const float4*)item,
                                                        (const uint4*)buf1,
                                                        (float4*)out);
}